// Round 17
// baseline (694.060 us; speedup 1.0000x reference)
//
#include <hip/hip_runtime.h>
#include <cstdio>
#include <math.h>

typedef unsigned short u16;
typedef float f32x4 __attribute__((ext_vector_type(4)));
typedef float f32x16 __attribute__((ext_vector_type(16)));
typedef __bf16 bf16x8 __attribute__((ext_vector_type(8)));
typedef u16 u16x4 __attribute__((ext_vector_type(4)));
typedef u16 u16x8 __attribute__((ext_vector_type(8)));

__device__ __forceinline__ u16 f2bf(float x) {
  unsigned u = __float_as_uint(x);
  u = (u + 0x7FFFu + ((u >> 16) & 1u)) >> 16;
  return (u16)u;
}
__device__ __forceinline__ float bf2f(u16 x) {
  return __uint_as_float(((unsigned)x) << 16);
}

__device__ __forceinline__ f32x16 mfma32(bf16x8 a, bf16x8 b, f32x16 c) {
  return __builtin_amdgcn_mfma_f32_32x32x16_bf16(a, b, c, 0, 0, 0);
}

// async global->LDS, 16B per lane. LDS dest = wave-uniform base + lane*16.
__device__ __forceinline__ void gload_lds16(const void* g, void* l) {
  __builtin_amdgcn_global_load_lds(
      (const __attribute__((address_space(1))) void*)g,
      (__attribute__((address_space(3))) void*)l, 16, 0, 0);
}

// C[m,n] = scale * sum_k A[m,k] * B[n,k].  BM=BN=256, BK=64, 512 thr = 8 waves
// (2M x 4N), per-wave 128x64 out. LDS 128KB = 2 buf x {A 32K + B' 32K}.
//
// r17 change: core moved from mfma 16x16x32 to 32x32x16 (m119: +20% per-FLOP
// ceiling; half the MFMA instructions + half the dep chains per phase).
// Session model (r16): everything runs ~600 TF with near-zero quantization
// waste; the gap to m201's 1563 is per-instruction core overhead.
// Per-wave 128x64 = 4 m-subtiles(32) x 2 n-subtiles(32); acc = 8 x f32x16.
// Frag layouts: C/D col=lane&31, row=(reg&3)+8*(reg>>2)+4*(lane>>5)
// [m74/m101-verified]; A row=lane&31,k=(lane>>5)*8+e; B col=lane&31,same-k
// (family analogy w/ verified 16x16x32 mapping; refcheck catches if wrong).
//
// Stage/wait skeleton UNCHANGED from r15 (chunks = same bytes, same order):
// 8 phases / 2 K-tiles, counted vmcnt(6) at ph4/ph8 only, chunk flow
// {ph1:A0+Blo, ph2:Bhi, ph3:A1, ph4:regs} x {buf0,buf1}; stage slots as r15
// proof table. Per phase now 8 MFMA of 32x32x16 (same FLOPs).
// Swizzle: gload-staged regions phys slot = logical ^ (row&7), row&7 ==
// lane&7 for all frag reads (32-row subtiles are 0 mod 32). TCVT-written
// regions f(row) = (row&7)^((row>>2)&7) -> read term (lane&7)^((lane>>2)&7),
// m-independent. All read groups 2 lanes/slot per 16-lane phase = free.
// Block-index modes:
//  PVLPT zigzag: grid (x=z16, y=o4, z=zz8); tb = zz<4 ? 7-zz : zz-4.
//  TRI: compact causal grid, gridDim.x == 36 tiles of 8x8 triangular tiling.
//  SWZ: chunked XCD swizzle on flattened id (identity unless nwg%8==0).
//  QKM: z in {0,1} selects {B,Tf,Cv} vs {B2,Tf2,Cv2} (merged Q+K proj).
template <bool BF16OUT, bool SWZ, bool TRI, bool KLIMIT, bool PVLPT, int TMODE, bool QKM>
__global__ __launch_bounds__(512, 2) void gemm_bt(
    const u16* __restrict__ A, const u16* B, const u16* B2,
    const float* Tf, const float* Tf2, void* Cv, void* Cv2,
    int K, int lda, int ldb, int ldc,
    long long sAz, long long sBz, long long sCz, float scale)
{
  int bx, by, z;
  if (PVLPT) {
    z = (int)blockIdx.x; by = (int)blockIdx.y;
    const int zz = (int)blockIdx.z;
    bx = (zz < 4) ? (7 - zz) : (zz - 4);  // zigzag: RR pair sums uniform
  } else {
    const int gx = gridDim.x, gy = gridDim.y;
    const int nwg = gx * gy * gridDim.z;
    int f = blockIdx.x + gx * (blockIdx.y + gy * blockIdx.z);
    if (SWZ && (nwg & 7) == 0) f = (f & 7) * (nwg >> 3) + (f >> 3);
    if (TRI) {
      const int j = f % gx;  // gx == 36
      z = f / gx;
      int r = (int)((sqrtf(8.f * j + 1.f) - 1.f) * 0.5f);
      while (r * (r + 1) / 2 > j) --r;
      while ((r + 1) * (r + 2) / 2 <= j) ++r;
      by = r;
      bx = j - r * (r + 1) / 2;
    } else {
      bx = f % gx;
      const int rest = f / gx;
      by = rest % gy;
      z = rest / gy;
    }
  }
  if (QKM) {
    if (z == 1) { B = B2; Tf = Tf2; Cv = Cv2; }
    z = 0;
  }

  const int n0 = bx * 256;
  const int m0 = by * 256;
  A += (long long)z * sAz;
  B += (long long)z * sBz;

  const int tid = threadIdx.x;
  const int wave = tid >> 6, lane = tid & 63;
  const int wr = wave >> 2, wc = wave & 3;  // 2M x 4N wave grid

  // per buffer (32768 u16): A [256][64] at 0..16383; B' halves at 16384 +
  // half*8192, local row lr = wc*32 + (lane&31) within each half.
  __shared__ u16 lds[2][32768];

  f32x16 acc[4][2] = {};  // [m-subtile 32][n-subtile 32]

  int kEnd = K;
  if (KLIMIT || PVLPT) { int ke = n0 + 256; kEnd = ke < K ? ke : K; }
  const int nt = kEnd >> 6;

  // ---- gload staging (phys slot = logical ^ (row&7), pre-swizzled source):
  const int sOff = ((lane & 7) ^ ((lane >> 3) & 7)) * 8;  // elem offset in row
  const int r0 = wave * 8 + (lane >> 3);                  // row within call
  const u16* gA0 = A + (long long)(m0 + r0) * lda + sOff;

  // ---- transpose source (fp32, [k][2048])
  const float* Tsrc = nullptr;
  if (TMODE == 1) Tsrc = Tf + ((long long)(m0 >> 11) * 1024) * 2048 + (m0 & 2047);
  else if (TMODE == 2) Tsrc = Tf + ((long long)z * 1024) * 2048 + n0;
  const int tcol = lane * 4;
  f32x4 tv[8];

  // ---- read swizzle terms (lane-only; 32-row subtiles are 0 mod 32):
  const int swzA = (lane & 7) ^ ((TMODE == 1) ? ((lane >> 2) & 7) : 0);
  const int swzB = (lane & 7) ^ ((TMODE == 2) ? ((lane >> 2) & 7) : 0);
  const int l31 = lane & 31, lhi = lane >> 5;

// A frag: row = wr*128 + mm*32 + l31; k-step ks (K=16): slot = ks*2 + lhi
#define AOFF32(mm, ks) ((wr * 128 + (mm) * 32 + l31) * 64 + \
                        ((((ks) * 2 + lhi) ^ swzA)) * 8)
// B frag: half nn, local row wc*32 + l31
#define BOFF32(nn, ks) (16384 + (nn) * 8192 + (wc * 32 + l31) * 64 + \
                        ((((ks) * 2 + lhi) ^ swzB)) * 8)

// A chunk stagers: A0 = calls 0,2 (rows wr*128+0..63); A1 = calls 1,3
#define STAGE_A0(T, BUF)                                                       \
  {                                                                            \
    const long long kc = (long long)(T) * 64;                                  \
    gload_lds16(gA0 + kc, &lds[BUF][wave * 512]);                              \
    gload_lds16(gA0 + (long long)128 * lda + kc,                               \
                &lds[BUF][2 * 4096 + wave * 512]);                             \
  }
#define STAGE_A1(T, BUF)                                                       \
  {                                                                            \
    const long long kc = (long long)(T) * 64;                                  \
    gload_lds16(gA0 + (long long)64 * lda + kc,                                \
                &lds[BUF][1 * 4096 + wave * 512]);                             \
    gload_lds16(gA0 + (long long)192 * lda + kc,                               \
                &lds[BUF][3 * 4096 + wave * 512]);                             \
  }
#define STAGE_A(T, BUF, H)                                                     \
  {                                                                            \
    const long long kc = (long long)(T) * 64;                                  \
    _Pragma("unroll")                                                          \
    for (int c = (H) * 2; c < (H) * 2 + 2; ++c)                                \
      gload_lds16(gA0 + (long long)(c * 64) * lda + kc,                        \
                  &lds[BUF][c * 4096 + wave * 512]);                           \
  }
#define STAGE_B(T, BUF, H)                                                     \
  {                                                                            \
    const long long kc = (long long)(T) * 64;                                  \
    _Pragma("unroll")                                                          \
    for (int c = (H) * 2; c < (H) * 2 + 2; ++c) {                              \
      const int rp = (c & 1) * 64 + r0;                                        \
      const int row = (rp >> 5) * 64 + (c >> 1) * 32 + (rp & 31);              \
      gload_lds16(B + (long long)(n0 + row) * ldb + sOff + kc,                 \
                  &lds[BUF][16384 + c * 4096 + wave * 512]);                   \
    }                                                                          \
  }
// issue 8 fp32 rows of tile T (k = T*64 + wave*8 + r)
#define TLOAD(T)                                                               \
  _Pragma("unroll")                                                            \
  for (int r = 0; r < 8; ++r)                                                  \
    tv[r] = *(const f32x4*)(Tsrc + (long long)((T) * 64 + wave * 8 + r) * 2048 + tcol);
// cvt + transpose-in-regs + 4 x ds_write_b128 into buf BUF
#define TCVT(BUF)                                                              \
  _Pragma("unroll")                                                            \
  for (int j = 0; j < 4; ++j) {                                                \
    const int rw = (lane << 2) + j;                                            \
    u16x8 hv;                                                                  \
    _Pragma("unroll")                                                          \
    for (int r = 0; r < 8; ++r) hv[r] = f2bf(tv[r][j]);                        \
    int ad;                                                                    \
    if (TMODE == 1) {                                                          \
      ad = rw * 64 + ((wave ^ ((rw & 7) ^ ((rw >> 2) & 7))) * 8);              \
    } else {                                                                   \
      const int h = (rw >> 5) & 1, rp = (rw >> 6) * 32 + (rw & 31);            \
      ad = 16384 + h * 8192 + rp * 64 +                                        \
           ((wave ^ ((rp & 7) ^ ((rp >> 2) & 7))) * 8);                        \
    }                                                                          \
    *(u16x8*)(&lds[BUF][ad]) = hv;                                             \
  }

  bf16x8 pA[8], pBlo[4], pBhi[4];
// read m-half mh (subtiles mh*2, mh*2+1), all 4 k-steps: 8 b128
#define READ_A(base, mh)                                                       \
  _Pragma("unroll")                                                            \
  for (int mm = 0; mm < 2; ++mm)                                               \
    _Pragma("unroll")                                                          \
    for (int ks = 0; ks < 4; ++ks)                                             \
      pA[mm * 4 + ks] = *(const bf16x8*)((base) + AOFF32((mh) * 2 + mm, ks));
#define READ_BLO(base)                                                         \
  _Pragma("unroll")                                                            \
  for (int ks = 0; ks < 4; ++ks)                                               \
    pBlo[ks] = *(const bf16x8*)((base) + BOFF32(0, ks));
#define READ_BHI(base)                                                         \
  _Pragma("unroll")                                                            \
  for (int ks = 0; ks < 4; ++ks)                                               \
    pBhi[ks] = *(const bf16x8*)((base) + BOFF32(1, ks));
// 8 MFMA: m-half mh x n-subtile nn over K=64
#define MFMA8(mh, P, nn)                                                       \
  _Pragma("unroll")                                                            \
  for (int mm = 0; mm < 2; ++mm)                                               \
    _Pragma("unroll")                                                          \
    for (int ks = 0; ks < 4; ++ks)                                             \
      acc[(mh) * 2 + mm][nn] = mfma32(pA[mm * 4 + ks], P[ks], acc[(mh) * 2 + mm][nn]);

#define BAR()   asm volatile("s_barrier" ::: "memory")
#define VM(N)   asm volatile("s_waitcnt vmcnt(" #N ")" ::: "memory")
#define LGKMW() asm volatile("s_waitcnt lgkmcnt(0)" ::: "memory")
#define PRIO1() __builtin_amdgcn_s_setprio(1)
#define PRIO0() __builtin_amdgcn_s_setprio(0)

  if constexpr (TMODE == 0) {
    // ---- 8-phase / 2-K-tile counted-vmcnt pipeline (r15 skeleton) ----
    const u16* b0 = &lds[0][0];
    const u16* b1 = &lds[1][0];
    STAGE_A0(0, 0) STAGE_B(0, 0, 0) STAGE_B(0, 0, 1) STAGE_A1(0, 0)
    STAGE_A0(1, 1) STAGE_B(1, 1, 0) STAGE_B(1, 1, 1) STAGE_A1(1, 1)
    VM(8);
    BAR();
    const int npairs = nt >> 1;
    for (int j = 0; j < npairs; ++j) {
      const int t = 2 * j;
      const bool pf = (j + 1 < npairs);

      READ_A(b0, 0) READ_BLO(b0)
      BAR(); PRIO1(); MFMA8(0, pBlo, 0); PRIO0(); BAR();
      READ_BHI(b0)
      if (pf) STAGE_B(t + 2, 0, 0)
      BAR(); PRIO1(); MFMA8(0, pBhi, 1); PRIO0(); BAR();
      READ_A(b0, 1)
      if (pf) STAGE_B(t + 2, 0, 1)
      BAR(); PRIO1(); MFMA8(1, pBhi, 1); PRIO0(); BAR();
      if (pf) STAGE_A1(t + 2, 0)
      BAR(); PRIO1(); MFMA8(1, pBlo, 0); PRIO0();
      if (pf) VM(6); else VM(0);
      BAR();

      READ_A(b1, 0) READ_BLO(b1)
      if (pf) STAGE_A0(t + 2, 0)
      BAR(); PRIO1(); MFMA8(0, pBlo, 0); PRIO0(); BAR();
      READ_BHI(b1)
      if (pf) { STAGE_A0(t + 3, 1) STAGE_B(t + 3, 1, 0) }
      BAR(); PRIO1(); MFMA8(0, pBhi, 1); PRIO0(); BAR();
      READ_A(b1, 1)
      if (pf) STAGE_B(t + 3, 1, 1)
      BAR(); PRIO1(); MFMA8(1, pBhi, 1); PRIO0(); BAR();
      if (pf) STAGE_A1(t + 3, 1)
      BAR(); PRIO1(); MFMA8(1, pBlo, 0); PRIO0();
      if (pf) VM(6); else VM(0);
      BAR();
    }
  } else {
    // ---- fused-transpose loop (r14 skeleton) ----
    TLOAD(0)
    if (TMODE == 1) { STAGE_B(0, 0, 0) STAGE_B(0, 0, 1) }
    else            { STAGE_A(0, 0, 0) STAGE_A(0, 0, 1) }
    VM(0);
    TCVT(0)
    LGKMW();
    BAR();
    for (int t = 0; t < nt; ++t) {
      const u16* bb = &lds[t & 1][0];
      const int nxb = (t + 1) & 1;
      const bool pf = (t + 1 < nt);

      if (pf) {
        TLOAD(t + 1)   // 8 dwordx4 (issued first -> oldest in VMEM FIFO)
        if (TMODE == 1) { STAGE_B(t + 1, nxb, 0) STAGE_B(t + 1, nxb, 1) }
        else            { STAGE_A(t + 1, nxb, 0) STAGE_A(t + 1, nxb, 1) }
      }

      READ_A(bb, 0) READ_BLO(bb)
      BAR(); PRIO1(); MFMA8(0, pBlo, 0); PRIO0(); BAR();

      READ_BHI(bb)
      BAR(); PRIO1(); MFMA8(0, pBhi, 1); PRIO0(); BAR();

      READ_A(bb, 1)
      BAR(); PRIO1(); MFMA8(1, pBhi, 1); PRIO0();
      if (pf) { VM(2); TCVT(nxb) }   // overlap: 8 TLOADs retired, 2 DMAs fly
      BAR();

      BAR(); PRIO1(); MFMA8(1, pBlo, 0); PRIO0();
      VM(0);   // 2 DMAs issued a full tile ago -> no stall
      LGKMW(); // TCVT ds_writes visible to other waves
      BAR();
    }
  }
#undef STAGE_A0
#undef STAGE_A1
#undef STAGE_A
#undef STAGE_B
#undef TLOAD
#undef TCVT
#undef READ_A
#undef READ_BLO
#undef READ_BHI
#undef MFMA8
#undef AOFF32
#undef BOFF32
#undef BAR
#undef VM
#undef LGKMW
#undef PRIO1
#undef PRIO0

  // C/D layout (32x32): col = lane&31, row = (reg&3)+8*(reg>>2)+4*(lane>>5)
  // [m74/m101-verified]
  const int crow0 = m0 + wr * 128 + 4 * lhi;
  const int ccol0 = n0 + wc * 64 + l31;
  if (BF16OUT) {
    u16* C = (u16*)Cv + (long long)z * sCz;
#pragma unroll
    for (int m = 0; m < 4; ++m)
#pragma unroll
      for (int n = 0; n < 2; ++n)
#pragma unroll
        for (int reg = 0; reg < 16; ++reg) {
          const int r = crow0 + m * 32 + (reg & 3) + 8 * (reg >> 2);
          C[(long long)r * ldc + ccol0 + n * 32] = f2bf(acc[m][n][reg] * scale);
        }
  } else {
    float* C = (float*)Cv + (long long)z * sCz;
#pragma unroll
    for (int m = 0; m < 4; ++m)
#pragma unroll
      for (int n = 0; n < 2; ++n)
#pragma unroll
        for (int reg = 0; reg < 16; ++reg) {
          const int r = crow0 + m * 32 + (reg & 3) + 8 * (reg >> 2);
          C[(long long)r * ldc + ccol0 + n * 32] = acc[m][n][reg] * scale;
        }
  }
}

__global__ __launch_bounds__(256) void conv_weights(
    const float* __restrict__ a, const float* __restrict__ b, const float* __restrict__ c,
    u16* __restrict__ oa, u16* __restrict__ ob, u16* __restrict__ oc)
{
  const int which = blockIdx.y;
  const float* s = which == 0 ? a : which == 1 ? b : c;
  u16* d = which == 0 ? oa : which == 1 ? ob : oc;
  const int idx = (blockIdx.x * 256 + threadIdx.x) * 4;
  f32x4 v = *(const f32x4*)(s + idx);
  u16x4 o;
#pragma unroll
  for (int j = 0; j < 4; ++j) o[j] = f2bf(v[j]);
  *(u16x4*)(d + idx) = o;
}

// WAVE-per-row softmax, in place. Each wave owns one row t (32 elems/lane,
// 4 coalesced u16x8 chunks); reduction via __shfl_xor only. Block 256 = 4
// rows; grid (512, 16). Masked (s>t) -> exp underflow 0 (PV needs zeros).
__global__ __launch_bounds__(256) void col_softmax(u16* __restrict__ S)
{
  const int wid = threadIdx.x >> 6, lane = threadIdx.x & 63;
  const int t = blockIdx.x * 4 + wid;
  u16* row = S + ((long long)blockIdx.y * 2048 + t) * 2048;

  u16x8 a[4];
#pragma unroll
  for (int c = 0; c < 4; ++c) a[c] = *(const u16x8*)(row + c * 512 + lane * 8);

  float v[32];
  float m = -1e30f;
#pragma unroll
  for (int c = 0; c < 4; ++c)
#pragma unroll
    for (int j = 0; j < 8; ++j) {
      const int idx = c * 512 + lane * 8 + j;
      v[c * 8 + j] = (idx <= t) ? bf2f(a[c][j]) : -1e30f;
      m = fmaxf(m, v[c * 8 + j]);
    }
#pragma unroll
  for (int off = 32; off; off >>= 1) m = fmaxf(m, __shfl_xor(m, off));

  float ssum = 0.f;
#pragma unroll
  for (int i = 0; i < 32; ++i) { v[i] = __expf(v[i] - m); ssum += v[i]; }
#pragma unroll
  for (int off = 32; off; off >>= 1) ssum += __shfl_xor(ssum, off);
  const float inv = 1.0f / ssum;

#pragma unroll
  for (int c = 0; c < 4; ++c) {
    u16x8 o;
#pragma unroll
    for (int j = 0; j < 8; ++j) o[j] = f2bf(v[c * 8 + j] * inv);
    *(u16x8*)(row + c * 512 + lane * 8) = o;
  }
}

extern "C" void kernel_launch(void* const* d_in, const int* in_sizes, int n_in,
                              void* d_out, int out_size, void* d_ws, size_t ws_size,
                              hipStream_t stream)
{
  const float* Q  = (const float*)d_in[0];
  const float* K  = (const float*)d_in[1];
  const float* V  = (const float*)d_in[2];
  const float* WQ = (const float*)d_in[3];
  const float* WK = (const float*)d_in[4];
  const float* WV = (const float*)d_in[5];
  float* out = (float*)d_out;

  const size_t MB = 1ull << 20;
  char* w = (char*)d_ws;
  if (ws_size < 326 * MB) {
    fprintf(stderr, "kernel_launch: workspace too small (%zu B, need >= %zu B)\n",
            ws_size, (size_t)(326 * MB));
    return;
  }

  // ws layout (MB): [0,6) weights bf16 | [6,70) Qd_t | [70,134) Kd_t |
  // [134,198) Vd | [198,326) S bf16 all 16 batches (in-place softmax, no P).
  u16* wq  = (u16*)(w + 0 * MB);
  u16* wk  = (u16*)(w + 2 * MB);
  u16* wv  = (u16*)(w + 4 * MB);
  u16* qdt = (u16*)(w + 6 * MB);
  u16* kdt = (u16*)(w + 70 * MB);
  u16* vd  = (u16*)(w + 134 * MB);
  u16* S   = (u16*)(w + 198 * MB);

  conv_weights<<<dim3(1024, 3), 256, 0, stream>>>(WQ, WK, WV, wq, wk, wv);

  // Q-proj + K-proj merged: grid (4,128,2), z picks {Q,wq,qdt} vs {K,wk,kdt}.
  gemm_bt<true, true, false, false, false, 1, true><<<dim3(4, 128, 2), 512, 0, stream>>>(
      wq, wq, wk, Q, K, qdt, kdt, 1024, 0, 1024, 1024, 0, 0, 0, 1.0f);
  // Vd (o, s) per batch: TMODE=2 (B = trans(V) from fp32), A = wv.
  gemm_bt<true, true, false, false, false, 2, false><<<dim3(8, 4, 16), 512, 0, stream>>>(
      wv, wv, nullptr, V, nullptr, vd, nullptr, 1024, 1024, 0, 2048,
      0, 0, (long long)1024 * 2048, 1.0f);

  // S'[t,s] = Kd_t[t,:]·Qd_t[s,:]/32 — compact triangular grid, 36 tiles/z
  // x 16 z = 576 blocks, chunked XCD swizzle.
  gemm_bt<true, true, true, false, false, 0, false><<<dim3(36, 1, 16), 512, 0, stream>>>(
      kdt, qdt, nullptr, nullptr, nullptr, S, nullptr, 1024, 1024, 1024, 2048,
      (long long)2048 * 1024, (long long)2048 * 1024, (long long)2048 * 2048, 0.03125f);
  // row-softmax over s (masked by index), IN PLACE, wave-per-row
  col_softmax<<<dim3(512, 16), 256, 0, stream>>>(S);
  // out[o,t] = sum_s Vd[o,s] P[t,s] — single dispatch, causal K-limit,
  // zigzag tb mapping for RR balance.
  gemm_bt<false, false, false, true, true, 0, false><<<dim3(16, 4, 8), 512, 0, stream>>>(
      vd, S, nullptr, nullptr, nullptr, out, nullptr, 2048, 2048, 2048, 2048,
      (long long)1024 * 2048, (long long)2048 * 2048, (long long)1024 * 2048, 1.0f);
}

// Round 18
// 563.519 us; speedup vs baseline: 1.2317x; 1.2317x over previous
//
#include <hip/hip_runtime.h>
#include <cstdio>
#include <math.h>

typedef unsigned short u16;
typedef float f32x4 __attribute__((ext_vector_type(4)));
typedef __bf16 bf16x8 __attribute__((ext_vector_type(8)));
typedef u16 u16x4 __attribute__((ext_vector_type(4)));
typedef u16 u16x8 __attribute__((ext_vector_type(8)));

__device__ __forceinline__ u16 f2bf(float x) {
  unsigned u = __float_as_uint(x);
  u = (u + 0x7FFFu + ((u >> 16) & 1u)) >> 16;
  return (u16)u;
}
__device__ __forceinline__ float bf2f(u16 x) {
  return __uint_as_float(((unsigned)x) << 16);
}

__device__ __forceinline__ f32x4 mfma_bf16(bf16x8 a, bf16x8 b, f32x4 c) {
  return __builtin_amdgcn_mfma_f32_16x16x32_bf16(a, b, c, 0, 0, 0);
}

// async global->LDS, 16B per lane. LDS dest = wave-uniform base + lane*16.
__device__ __forceinline__ void gload_lds16(const void* g, void* l) {
  __builtin_amdgcn_global_load_lds(
      (const __attribute__((address_space(1))) void*)g,
      (__attribute__((address_space(3))) void*)l, 16, 0, 0);
}

// C[m,n] = scale * sum_k A[m,k] * B[n,k].  BM=BN=256, BK=64, 512 thr = 8 waves
// (2M x 4N), per-wave 128x64 out. LDS 128KB = 2 buf x {A 32K + B' 32K}.
//
// r18 = REVERT to r16 (best state, 562-564us). r17's 32x32 core is
// falsified: bank = slot*4 mod 32 (row stride 128B kills row term), so a
// 32-lane column read has only 8 slots -> 4-way conflict (4.19e6 measured,
// proj 138->300us). The 16-row fragment keeps 2 lanes/slot = free.
// Session model: GEMM core is staging-throughput-bound (~10 B/cyc/CU,
// schedule-invariant across 9 variants r7-r15); topology waste ~0 (r16).
//
// TMODE=0: 8-phase / 2-K-tile counted-vmcnt pipeline (r15 proof table).
// TMODE=1/2: fused TRANSPOSE+CVT from fp32 k-major Tf ([k][2048]);
//   TCVT overlapped after ph3; end-of-tile VM(0)+lgkmcnt(0).
// Swizzle: gload-staged regions slot^=row&7 (pre-swizzled source);
//   reg-written regions f(row)=(row&7)^((row>>2)&7). Conflicts measured 0.
// Block-index modes:
//  PVLPT zigzag: grid (x=z16, y=o4, z=zz8); tb = zz<4 ? 7-zz : zz-4 (RR
//    pairs sum uniform).
//  TRI: compact causal grid, gridDim.x == 36 tiles of 8x8 triangular tiling.
//  SWZ: chunked XCD swizzle on flattened id (identity unless nwg%8==0).
//  QKM: z in {0,1} selects {B,Tf,Cv} vs {B2,Tf2,Cv2} (merged Q+K proj).
template <bool BF16OUT, bool SWZ, bool TRI, bool KLIMIT, bool PVLPT, int TMODE, bool QKM>
__global__ __launch_bounds__(512, 2) void gemm_bt(
    const u16* __restrict__ A, const u16* B, const u16* B2,
    const float* Tf, const float* Tf2, void* Cv, void* Cv2,
    int K, int lda, int ldb, int ldc,
    long long sAz, long long sBz, long long sCz, float scale)
{
  int bx, by, z;
  if (PVLPT) {
    z = (int)blockIdx.x; by = (int)blockIdx.y;
    const int zz = (int)blockIdx.z;
    bx = (zz < 4) ? (7 - zz) : (zz - 4);  // zigzag: RR pair sums 9 units
  } else {
    const int gx = gridDim.x, gy = gridDim.y;
    const int nwg = gx * gy * gridDim.z;
    int f = blockIdx.x + gx * (blockIdx.y + gy * blockIdx.z);
    if (SWZ && (nwg & 7) == 0) f = (f & 7) * (nwg >> 3) + (f >> 3);
    if (TRI) {
      const int j = f % gx;  // gx == 36
      z = f / gx;
      int r = (int)((sqrtf(8.f * j + 1.f) - 1.f) * 0.5f);
      while (r * (r + 1) / 2 > j) --r;
      while ((r + 1) * (r + 2) / 2 <= j) ++r;
      by = r;
      bx = j - r * (r + 1) / 2;
    } else {
      bx = f % gx;
      const int rest = f / gx;
      by = rest % gy;
      z = rest / gy;
    }
  }
  if (QKM) {
    if (z == 1) { B = B2; Tf = Tf2; Cv = Cv2; }
    z = 0;
  }

  const int n0 = bx * 256;
  const int m0 = by * 256;
  A += (long long)z * sAz;
  B += (long long)z * sBz;

  const int tid = threadIdx.x;
  const int wave = tid >> 6, lane = tid & 63;
  const int wr = wave >> 2, wc = wave & 3;  // 2M x 4N wave grid

  // per buffer (32768 u16): A [256][64] at 0..16383; B' halves at 16384 +
  // half*8192 + r'[0..127]*64.
  __shared__ u16 lds[2][32768];

  f32x4 acc[8][4] = {};

  int kEnd = K;
  if (KLIMIT || PVLPT) { int ke = n0 + 256; kEnd = ke < K ? ke : K; }
  const int nt = kEnd >> 6;

  // ---- gload staging (swizzle slot^=row&7, pre-swizzled source):
  const int sOff = ((lane & 7) ^ ((lane >> 3) & 7)) * 8;  // elem offset in row
  const int r0 = wave * 8 + (lane >> 3);                  // row within call
  const u16* gA0 = A + (long long)(m0 + r0) * lda + sOff;

  // ---- transpose source (fp32, [k][2048])
  const float* Tsrc = nullptr;
  if (TMODE == 1) Tsrc = Tf + ((long long)(m0 >> 11) * 1024) * 2048 + (m0 & 2047);
  else if (TMODE == 2) Tsrc = Tf + ((long long)z * 1024) * 2048 + n0;
  const int tcol = lane * 4;
  f32x4 tv[8];

  // ---- read offsets. frag rows: A: wr*128+m*16+frow; B': wc*32+(n&1)*16+frow.
  const int frow = lane & 15, g = lane >> 4;
  const int swzA0 = (TMODE == 1) ? ((frow & 7) ^ (frow >> 2)) : (frow & 7);
  const int swzA1 = (TMODE == 1) ? ((frow & 7) ^ (4 + (frow >> 2))) : (frow & 7);
  const int swzB0 = (TMODE == 2) ? ((frow & 7) ^ (frow >> 2)) : (frow & 7);
  const int swzB1 = (TMODE == 2) ? ((frow & 7) ^ (4 + (frow >> 2))) : (frow & 7);

#define AOFF(m, kk) ((wr * 128 + (m) * 16 + frow) * 64 + \
                     (((kk) * 4 + g) ^ (((m) & 1) ? swzA1 : swzA0)) * 8)
#define BOFF(n, kk) (16384 + ((n) >> 1) * 8192 + (wc * 32 + ((n) & 1) * 16 + frow) * 64 + \
                     (((kk) * 4 + g) ^ (((n) & 1) ? swzB1 : swzB0)) * 8)

// A chunk stagers: A0 = calls 0,2 (frag rows of m0-3); A1 = calls 1,3 (m4-7)
#define STAGE_A0(T, BUF)                                                       \
  {                                                                            \
    const long long kc = (long long)(T) * 64;                                  \
    gload_lds16(gA0 + kc, &lds[BUF][wave * 512]);                              \
    gload_lds16(gA0 + (long long)128 * lda + kc,                               \
                &lds[BUF][2 * 4096 + wave * 512]);                             \
  }
#define STAGE_A1(T, BUF)                                                       \
  {                                                                            \
    const long long kc = (long long)(T) * 64;                                  \
    gload_lds16(gA0 + (long long)64 * lda + kc,                                \
                &lds[BUF][1 * 4096 + wave * 512]);                             \
    gload_lds16(gA0 + (long long)192 * lda + kc,                               \
                &lds[BUF][3 * 4096 + wave * 512]);                             \
  }
#define STAGE_A(T, BUF, H)                                                     \
  {                                                                            \
    const long long kc = (long long)(T) * 64;                                  \
    _Pragma("unroll")                                                          \
    for (int c = (H) * 2; c < (H) * 2 + 2; ++c)                                \
      gload_lds16(gA0 + (long long)(c * 64) * lda + kc,                        \
                  &lds[BUF][c * 4096 + wave * 512]);                           \
  }
#define STAGE_B(T, BUF, H)                                                     \
  {                                                                            \
    const long long kc = (long long)(T) * 64;                                  \
    _Pragma("unroll")                                                          \
    for (int c = (H) * 2; c < (H) * 2 + 2; ++c) {                              \
      const int rp = (c & 1) * 64 + r0;                                        \
      const int row = (rp >> 5) * 64 + (c >> 1) * 32 + (rp & 31);              \
      gload_lds16(B + (long long)(n0 + row) * ldb + sOff + kc,                 \
                  &lds[BUF][16384 + c * 4096 + wave * 512]);                   \
    }                                                                          \
  }
// issue 8 fp32 rows of tile T (k = T*64 + wave*8 + r)
#define TLOAD(T)                                                               \
  _Pragma("unroll")                                                            \
  for (int r = 0; r < 8; ++r)                                                  \
    tv[r] = *(const f32x4*)(Tsrc + (long long)((T) * 64 + wave * 8 + r) * 2048 + tcol);
// cvt + transpose-in-regs + 4 x ds_write_b128 into buf BUF
#define TCVT(BUF)                                                              \
  _Pragma("unroll")                                                            \
  for (int j = 0; j < 4; ++j) {                                                \
    const int rw = (lane << 2) + j;                                            \
    u16x8 hv;                                                                  \
    _Pragma("unroll")                                                          \
    for (int r = 0; r < 8; ++r) hv[r] = f2bf(tv[r][j]);                        \
    int ad;                                                                    \
    if (TMODE == 1) {                                                          \
      ad = rw * 64 + ((wave ^ ((rw & 7) ^ ((rw >> 2) & 7))) * 8);              \
    } else {                                                                   \
      const int h = (rw >> 5) & 1, rp = (rw >> 6) * 32 + (rw & 31);            \
      ad = 16384 + h * 8192 + rp * 64 +                                        \
           ((wave ^ ((rp & 7) ^ ((rp >> 2) & 7))) * 8);                        \
    }                                                                          \
    *(u16x8*)(&lds[BUF][ad]) = hv;                                             \
  }

  bf16x8 pA[8], pBlo[4], pBhi[4];
#define READ_A(base, mb)                                                       \
  _Pragma("unroll")                                                            \
  for (int i = 0; i < 4; ++i) {                                                \
    pA[i * 2 + 0] = *(const bf16x8*)((base) + AOFF((mb) + i, 0));              \
    pA[i * 2 + 1] = *(const bf16x8*)((base) + AOFF((mb) + i, 1));              \
  }
#define READ_BLO(base)                                                         \
  _Pragma("unroll")                                                            \
  for (int i = 0; i < 2; ++i) {                                                \
    pBlo[i * 2 + 0] = *(const bf16x8*)((base) + BOFF(i, 0));                   \
    pBlo[i * 2 + 1] = *(const bf16x8*)((base) + BOFF(i, 1));                   \
  }
#define READ_BHI(base)                                                         \
  _Pragma("unroll")                                                            \
  for (int i = 0; i < 2; ++i) {                                                \
    pBhi[i * 2 + 0] = *(const bf16x8*)((base) + BOFF(2 + i, 0));               \
    pBhi[i * 2 + 1] = *(const bf16x8*)((base) + BOFF(2 + i, 1));               \
  }
#define MFMA16(mb, nb, P)                                                      \
  _Pragma("unroll")                                                            \
  for (int i = 0; i < 4; ++i)                                                  \
    _Pragma("unroll")                                                          \
    for (int j = 0; j < 2; ++j) {                                              \
      acc[(mb) + i][(nb) + j] =                                                \
          mfma_bf16(pA[i * 2 + 0], P[j * 2 + 0], acc[(mb) + i][(nb) + j]);     \
      acc[(mb) + i][(nb) + j] =                                                \
          mfma_bf16(pA[i * 2 + 1], P[j * 2 + 1], acc[(mb) + i][(nb) + j]);     \
    }

#define BAR()   asm volatile("s_barrier" ::: "memory")
#define VM(N)   asm volatile("s_waitcnt vmcnt(" #N ")" ::: "memory")
#define LGKMW() asm volatile("s_waitcnt lgkmcnt(0)" ::: "memory")
#define PRIO1() __builtin_amdgcn_s_setprio(1)
#define PRIO0() __builtin_amdgcn_s_setprio(0)

  if constexpr (TMODE == 0) {
    // ---- 8-phase / 2-K-tile counted-vmcnt pipeline (r15 proof table) ----
    const u16* b0 = &lds[0][0];
    const u16* b1 = &lds[1][0];
    STAGE_A0(0, 0) STAGE_B(0, 0, 0) STAGE_B(0, 0, 1) STAGE_A1(0, 0)
    STAGE_A0(1, 1) STAGE_B(1, 1, 0) STAGE_B(1, 1, 1) STAGE_A1(1, 1)
    VM(8);
    BAR();
    const int npairs = nt >> 1;
    for (int j = 0; j < npairs; ++j) {
      const int t = 2 * j;
      const bool pf = (j + 1 < npairs);

      READ_A(b0, 0) READ_BLO(b0)
      BAR(); PRIO1(); MFMA16(0, 0, pBlo); PRIO0(); BAR();
      READ_BHI(b0)
      if (pf) STAGE_B(t + 2, 0, 0)
      BAR(); PRIO1(); MFMA16(0, 2, pBhi); PRIO0(); BAR();
      READ_A(b0, 4)
      if (pf) STAGE_B(t + 2, 0, 1)
      BAR(); PRIO1(); MFMA16(4, 2, pBhi); PRIO0(); BAR();
      if (pf) STAGE_A1(t + 2, 0)
      BAR(); PRIO1(); MFMA16(4, 0, pBlo); PRIO0();
      if (pf) VM(6); else VM(0);
      BAR();

      READ_A(b1, 0) READ_BLO(b1)
      if (pf) STAGE_A0(t + 2, 0)
      BAR(); PRIO1(); MFMA16(0, 0, pBlo); PRIO0(); BAR();
      READ_BHI(b1)
      if (pf) { STAGE_A0(t + 3, 1) STAGE_B(t + 3, 1, 0) }
      BAR(); PRIO1(); MFMA16(0, 2, pBhi); PRIO0(); BAR();
      READ_A(b1, 4)
      if (pf) STAGE_B(t + 3, 1, 1)
      BAR(); PRIO1(); MFMA16(4, 2, pBhi); PRIO0(); BAR();
      if (pf) STAGE_A1(t + 3, 1)
      BAR(); PRIO1(); MFMA16(4, 0, pBlo); PRIO0();
      if (pf) VM(6); else VM(0);
      BAR();
    }
  } else {
    // ---- fused-transpose loop (r14, TCVT overlapped after ph3) ----
    TLOAD(0)
    if (TMODE == 1) { STAGE_B(0, 0, 0) STAGE_B(0, 0, 1) }
    else            { STAGE_A(0, 0, 0) STAGE_A(0, 0, 1) }
    VM(0);
    TCVT(0)
    LGKMW();
    BAR();
    for (int t = 0; t < nt; ++t) {
      const u16* bb = &lds[t & 1][0];
      const int nxb = (t + 1) & 1;
      const bool pf = (t + 1 < nt);

      if (pf) {
        TLOAD(t + 1)   // 8 dwordx4 (issued first -> oldest in VMEM FIFO)
        if (TMODE == 1) { STAGE_B(t + 1, nxb, 0) STAGE_B(t + 1, nxb, 1) }
        else            { STAGE_A(t + 1, nxb, 0) STAGE_A(t + 1, nxb, 1) }
      }

      READ_A(bb, 0) READ_BLO(bb)
      BAR(); PRIO1(); MFMA16(0, 0, pBlo); PRIO0(); BAR();

      READ_BHI(bb)
      BAR(); PRIO1(); MFMA16(0, 2, pBhi); PRIO0(); BAR();

      READ_A(bb, 4)
      BAR(); PRIO1(); MFMA16(4, 2, pBhi); PRIO0();
      if (pf) { VM(2); TCVT(nxb) }   // overlap: 8 TLOADs retired, 2 DMAs fly
      BAR();

      BAR(); PRIO1(); MFMA16(4, 0, pBlo); PRIO0();
      VM(0);   // 2 DMAs issued a full tile ago -> no stall
      LGKMW(); // TCVT ds_writes visible to other waves
      BAR();
    }
  }
#undef STAGE_A0
#undef STAGE_A1
#undef STAGE_A
#undef STAGE_B
#undef TLOAD
#undef TCVT
#undef READ_A
#undef READ_BLO
#undef READ_BHI
#undef MFMA16
#undef AOFF
#undef BOFF
#undef BAR
#undef VM
#undef LGKMW
#undef PRIO1
#undef PRIO0

  // C/D layout: col = lane&15, row = (lane>>4)*4 + r  [m89-verified]
  const int crow0 = m0 + wr * 128 + (lane >> 4) * 4;
  const int ccol0 = n0 + wc * 64 + (lane & 15);
  if (BF16OUT) {
    u16* C = (u16*)Cv + (long long)z * sCz;
#pragma unroll
    for (int m = 0; m < 8; ++m)
#pragma unroll
      for (int n = 0; n < 4; ++n)
#pragma unroll
        for (int r = 0; r < 4; ++r)
          C[(long long)(crow0 + m * 16 + r) * ldc + ccol0 + n * 16] = f2bf(acc[m][n][r] * scale);
  } else {
    float* C = (float*)Cv + (long long)z * sCz;
#pragma unroll
    for (int m = 0; m < 8; ++m)
#pragma unroll
      for (int n = 0; n < 4; ++n)
#pragma unroll
        for (int r = 0; r < 4; ++r)
          C[(long long)(crow0 + m * 16 + r) * ldc + ccol0 + n * 16] = acc[m][n][r] * scale;
  }
}

__global__ __launch_bounds__(256) void conv_weights(
    const float* __restrict__ a, const float* __restrict__ b, const float* __restrict__ c,
    u16* __restrict__ oa, u16* __restrict__ ob, u16* __restrict__ oc)
{
  const int which = blockIdx.y;
  const float* s = which == 0 ? a : which == 1 ? b : c;
  u16* d = which == 0 ? oa : which == 1 ? ob : oc;
  const int idx = (blockIdx.x * 256 + threadIdx.x) * 4;
  f32x4 v = *(const f32x4*)(s + idx);
  u16x4 o;
#pragma unroll
  for (int j = 0; j < 4; ++j) o[j] = f2bf(v[j]);
  *(u16x4*)(d + idx) = o;
}

// WAVE-per-row softmax, in place. Each wave owns one row t (32 elems/lane,
// 4 coalesced u16x8 chunks); reduction via __shfl_xor only. Block 256 = 4
// rows; grid (512, 16). Masked (s>t) -> exp underflow 0 (PV needs zeros).
__global__ __launch_bounds__(256) void col_softmax(u16* __restrict__ S)
{
  const int wid = threadIdx.x >> 6, lane = threadIdx.x & 63;
  const int t = blockIdx.x * 4 + wid;
  u16* row = S + ((long long)blockIdx.y * 2048 + t) * 2048;

  u16x8 a[4];
#pragma unroll
  for (int c = 0; c < 4; ++c) a[c] = *(const u16x8*)(row + c * 512 + lane * 8);

  float v[32];
  float m = -1e30f;
#pragma unroll
  for (int c = 0; c < 4; ++c)
#pragma unroll
    for (int j = 0; j < 8; ++j) {
      const int idx = c * 512 + lane * 8 + j;
      v[c * 8 + j] = (idx <= t) ? bf2f(a[c][j]) : -1e30f;
      m = fmaxf(m, v[c * 8 + j]);
    }
#pragma unroll
  for (int off = 32; off; off >>= 1) m = fmaxf(m, __shfl_xor(m, off));

  float ssum = 0.f;
#pragma unroll
  for (int i = 0; i < 32; ++i) { v[i] = __expf(v[i] - m); ssum += v[i]; }
#pragma unroll
  for (int off = 32; off; off >>= 1) ssum += __shfl_xor(ssum, off);
  const float inv = 1.0f / ssum;

#pragma unroll
  for (int c = 0; c < 4; ++c) {
    u16x8 o;
#pragma unroll
    for (int j = 0; j < 8; ++j) o[j] = f2bf(v[c * 8 + j] * inv);
    *(u16x8*)(row + c * 512 + lane * 8) = o;
  }
}

extern "C" void kernel_launch(void* const* d_in, const int* in_sizes, int n_in,
                              void* d_out, int out_size, void* d_ws, size_t ws_size,
                              hipStream_t stream)
{
  const float* Q  = (const float*)d_in[0];
  const float* K  = (const float*)d_in[1];
  const float* V  = (const float*)d_in[2];
  const float* WQ = (const float*)d_in[3];
  const float* WK = (const float*)d_in[4];
  const float* WV = (const float*)d_in[5];
  float* out = (float*)d_out;

  const size_t MB = 1ull << 20;
  char* w = (char*)d_ws;
  if (ws_size < 326 * MB) {
    fprintf(stderr, "kernel_launch: workspace too small (%zu B, need >= %zu B)\n",
            ws_size, (size_t)(326 * MB));
    return;
  }

  // ws layout (MB): [0,6) weights bf16 | [6,70) Qd_t | [70,134) Kd_t |
  // [134,198) Vd | [198,326) S bf16 all 16 batches (in-place softmax, no P).
  u16* wq  = (u16*)(w + 0 * MB);
  u16* wk  = (u16*)(w + 2 * MB);
  u16* wv  = (u16*)(w + 4 * MB);
  u16* qdt = (u16*)(w + 6 * MB);
  u16* kdt = (u16*)(w + 70 * MB);
  u16* vd  = (u16*)(w + 134 * MB);
  u16* S   = (u16*)(w + 198 * MB);

  conv_weights<<<dim3(1024, 3), 256, 0, stream>>>(WQ, WK, WV, wq, wk, wv);

  // Q-proj + K-proj merged: grid (4,128,2), z picks {Q,wq,qdt} vs {K,wk,kdt}.
  gemm_bt<true, true, false, false, false, 1, true><<<dim3(4, 128, 2), 512, 0, stream>>>(
      wq, wq, wk, Q, K, qdt, kdt, 1024, 0, 1024, 1024, 0, 0, 0, 1.0f);
  // Vd (o, s) per batch: TMODE=2 (B = trans(V) from fp32), A = wv.
  gemm_bt<true, true, false, false, false, 2, false><<<dim3(8, 4, 16), 512, 0, stream>>>(
      wv, wv, nullptr, V, nullptr, vd, nullptr, 1024, 1024, 0, 2048,
      0, 0, (long long)1024 * 2048, 1.0f);

  // S'[t,s] = Kd_t[t,:]·Qd_t[s,:]/32 — compact triangular grid, 36 tiles/z
  // x 16 z = 576 blocks, chunked XCD swizzle.
  gemm_bt<true, true, true, false, false, 0, false><<<dim3(36, 1, 16), 512, 0, stream>>>(
      kdt, qdt, nullptr, nullptr, nullptr, S, nullptr, 1024, 1024, 1024, 2048,
      (long long)2048 * 1024, (long long)2048 * 1024, (long long)2048 * 2048, 0.03125f);
  // row-softmax over s (masked by index), IN PLACE, wave-per-row
  col_softmax<<<dim3(512, 16), 256, 0, stream>>>(S);
  // out[o,t] = sum_s Vd[o,s] P[t,s] — single dispatch, causal K-limit,
  // zigzag tb mapping for RR balance.
  gemm_bt<false, false, false, true, true, 0, false><<<dim3(16, 4, 8), 512, 0, stream>>>(
      vd, S, nullptr, nullptr, nullptr, out, nullptr, 2048, 2048, 2048, 2048,
      (long long)1024 * 2048, (long long)2048 * 2048, (long long)1024 * 2048, 1.0f);
}